// Round 1
// baseline (1360.975 us; speedup 1.0000x reference)
//
#include <hip/hip_runtime.h>

// ---------------------------------------------------------------------------
// DVGMamba forward. Round 7: 8-wave GEMM blocks (in-block K-split, 2 waves/SIMD)
// + add+rmsnorm fused into in_proj/fc1 GEMM prologues (residual ping-pong).
// b=2, l=64, S=256 tokens, D=512, DIN=1024, DS=16, DTR=32, K=4, Layers=8
// ---------------------------------------------------------------------------

#define NTOK 512
#define SEQ  256
#define CS   32     // scan chunk size
#define NC   8      // chunks

typedef __attribute__((ext_vector_type(8))) short bf16x8;
typedef __attribute__((ext_vector_type(16))) float f32x16;

__device__ __forceinline__ float silu_f(float x) { return x / (1.0f + expf(-x)); }
__device__ __forceinline__ float softplus_f(float x) {
  return (x > 20.0f) ? x : log1pf(expf(x));
}

// split fp32 -> (hi bf16, lo bf16) by truncation; packed 2x bf16 per dword
__device__ __forceinline__ void split_pack(float4 v, uint2* hi, uint2* lo) {
  uint ux = __float_as_uint(v.x), uy = __float_as_uint(v.y);
  uint uz = __float_as_uint(v.z), uw = __float_as_uint(v.w);
  hi->x = (ux >> 16) | (uy & 0xffff0000u);
  hi->y = (uz >> 16) | (uw & 0xffff0000u);
  float lx = v.x - __uint_as_float(ux & 0xffff0000u);
  float ly = v.y - __uint_as_float(uy & 0xffff0000u);
  float lz = v.z - __uint_as_float(uz & 0xffff0000u);
  float lw = v.w - __uint_as_float(uw & 0xffff0000u);
  lo->x = (__float_as_uint(lx) >> 16) | (__float_as_uint(ly) & 0xffff0000u);
  lo->y = (__float_as_uint(lz) >> 16) | (__float_as_uint(lw) & 0xffff0000u);
}

// --------------------------- split-bf16 MFMA NT GEMM -----------------------
// 512 threads = 8 waves. Waves 0-3 (group 0) consume k-half 0, waves 4-7
// (group 1) k-half 1 of each 32-K superstep; accumulators reduced via LDS.
__global__ __launch_bounds__(512) void gemm_bs_k(const float* __restrict__ A,
                                                 const float* __restrict__ B,
                                                 float* __restrict__ C,
                                                 int M, int N, int K, int Kc) {
  __shared__ alignas(16) ushort sAh[2][2][2][512];
  __shared__ alignas(16) ushort sAl[2][2][2][512];
  __shared__ alignas(16) ushort sBh[2][2][2][512];
  __shared__ alignas(16) ushort sBl[2][2][2][512];
  __shared__ alignas(64) float sRed[4096];
  int t = threadIdx.x;
  int bn = blockIdx.x, bm = blockIdx.y, z = blockIdx.z;
  const float* Ab = A + (size_t)bm * 64 * K + (size_t)z * Kc;
  const float* Bb = B + (size_t)bn * 64 * K + (size_t)z * Kc;
  float* Cb = C + (size_t)z * M * N;
  int r = t >> 3, kc = (t & 7) << 2;       // 64 rows x 32 k, one float4/thread
  int kh = kc >> 4, kc16 = kc & 15;
  int st = r >> 5, m = r & 31;
  int off = ((kc16 >> 3) << 8) + (m << 3) + (kc16 & 7);
  int w = t >> 6, lane = t & 63;
  int g = w >> 2, wq = w & 3;
  int wr = wq >> 1, wc = wq & 1;

  f32x16 acc;
#pragma unroll
  for (int i = 0; i < 16; ++i) acc[i] = 0.f;

  int ns = Kc >> 5;
  float4 a4 = *(const float4*)&Ab[(size_t)r * K + kc];
  float4 b4 = *(const float4*)&Bb[(size_t)r * K + kc];
  {
    uint2 hi, lo;
    split_pack(a4, &hi, &lo);
    *(uint2*)&sAh[0][kh][st][off] = hi; *(uint2*)&sAl[0][kh][st][off] = lo;
    split_pack(b4, &hi, &lo);
    *(uint2*)&sBh[0][kh][st][off] = hi; *(uint2*)&sBl[0][kh][st][off] = lo;
  }
  __syncthreads();
  for (int ssi = 0; ssi < ns; ++ssi) {
    int buf = ssi & 1;
    if (ssi + 1 < ns) {
      a4 = *(const float4*)&Ab[(size_t)r * K + (ssi + 1) * 32 + kc];
      b4 = *(const float4*)&Bb[(size_t)r * K + (ssi + 1) * 32 + kc];
    }
    bf16x8 ah = *(bf16x8*)&sAh[buf][g][wr][lane << 3];
    bf16x8 al = *(bf16x8*)&sAl[buf][g][wr][lane << 3];
    bf16x8 bh = *(bf16x8*)&sBh[buf][g][wc][lane << 3];
    bf16x8 bl = *(bf16x8*)&sBl[buf][g][wc][lane << 3];
    acc = __builtin_amdgcn_mfma_f32_32x32x16_bf16(ah, bh, acc, 0, 0, 0);
    acc = __builtin_amdgcn_mfma_f32_32x32x16_bf16(al, bh, acc, 0, 0, 0);
    acc = __builtin_amdgcn_mfma_f32_32x32x16_bf16(ah, bl, acc, 0, 0, 0);
    if (ssi + 1 < ns) {
      uint2 hi, lo;
      split_pack(a4, &hi, &lo);
      *(uint2*)&sAh[buf ^ 1][kh][st][off] = hi; *(uint2*)&sAl[buf ^ 1][kh][st][off] = lo;
      split_pack(b4, &hi, &lo);
      *(uint2*)&sBh[buf ^ 1][kh][st][off] = hi; *(uint2*)&sBl[buf ^ 1][kh][st][off] = lo;
    }
    __syncthreads();
  }
  if (g == 1) *(f32x16*)&sRed[(wq * 64 + lane) << 4] = acc;
  __syncthreads();
  if (g == 0) {
    f32x16 o = *(f32x16*)&sRed[(wq * 64 + lane) << 4];
#pragma unroll
    for (int i = 0; i < 16; ++i) acc[i] += o[i];
    int col = lane & 31, rq = lane >> 5;
    float* Cw = Cb + (size_t)(bm * 64 + wr * 32) * N + bn * 64 + wc * 32 + col;
#pragma unroll
    for (int rg = 0; rg < 16; ++rg) {
      int row = (rg & 3) + ((rg >> 2) << 3) + (rq << 2);
      Cw[(size_t)row * N] = acc[rg];
    }
  }
}

// --------------------------- GEMM with fused GLU on A ----------------------
// A_logical[r,k] = g[r*2048+k] * silu(g[r*2048+1024+k]); K = 1024.
__global__ __launch_bounds__(512) void gemm_glu_k(const float* __restrict__ G,
                                                  const float* __restrict__ B,
                                                  float* __restrict__ C,
                                                  int M, int N, int K, int Kc) {
  __shared__ alignas(16) ushort sAh[2][2][2][512];
  __shared__ alignas(16) ushort sAl[2][2][2][512];
  __shared__ alignas(16) ushort sBh[2][2][2][512];
  __shared__ alignas(16) ushort sBl[2][2][2][512];
  __shared__ alignas(64) float sRed[4096];
  int t = threadIdx.x;
  int bn = blockIdx.x, bm = blockIdx.y, z = blockIdx.z;
  const float* Gb = G + (size_t)bm * 64 * 2048 + (size_t)z * Kc;
  const float* Bb = B + (size_t)bn * 64 * K + (size_t)z * Kc;
  float* Cb = C + (size_t)z * M * N;
  int r = t >> 3, kc = (t & 7) << 2;
  int kh = kc >> 4, kc16 = kc & 15;
  int st = r >> 5, m = r & 31;
  int off = ((kc16 >> 3) << 8) + (m << 3) + (kc16 & 7);
  int w = t >> 6, lane = t & 63;
  int g = w >> 2, wq = w & 3;
  int wr = wq >> 1, wc = wq & 1;

  f32x16 acc;
#pragma unroll
  for (int i = 0; i < 16; ++i) acc[i] = 0.f;

  int ns = Kc >> 5;
  const float* gr = Gb + (size_t)r * 2048 + kc;
  float4 ga = *(const float4*)&gr[0];
  float4 gz = *(const float4*)&gr[1024];
  float4 b4 = *(const float4*)&Bb[(size_t)r * K + kc];
  {
    float4 a4 = {ga.x * silu_f(gz.x), ga.y * silu_f(gz.y),
                 ga.z * silu_f(gz.z), ga.w * silu_f(gz.w)};
    uint2 hi, lo;
    split_pack(a4, &hi, &lo);
    *(uint2*)&sAh[0][kh][st][off] = hi; *(uint2*)&sAl[0][kh][st][off] = lo;
    split_pack(b4, &hi, &lo);
    *(uint2*)&sBh[0][kh][st][off] = hi; *(uint2*)&sBl[0][kh][st][off] = lo;
  }
  __syncthreads();
  for (int ssi = 0; ssi < ns; ++ssi) {
    int buf = ssi & 1;
    if (ssi + 1 < ns) {
      ga = *(const float4*)&gr[(ssi + 1) * 32];
      gz = *(const float4*)&gr[1024 + (ssi + 1) * 32];
      b4 = *(const float4*)&Bb[(size_t)r * K + (ssi + 1) * 32 + kc];
    }
    bf16x8 ah = *(bf16x8*)&sAh[buf][g][wr][lane << 3];
    bf16x8 al = *(bf16x8*)&sAl[buf][g][wr][lane << 3];
    bf16x8 bh = *(bf16x8*)&sBh[buf][g][wc][lane << 3];
    bf16x8 bl = *(bf16x8*)&sBl[buf][g][wc][lane << 3];
    acc = __builtin_amdgcn_mfma_f32_32x32x16_bf16(ah, bh, acc, 0, 0, 0);
    acc = __builtin_amdgcn_mfma_f32_32x32x16_bf16(al, bh, acc, 0, 0, 0);
    acc = __builtin_amdgcn_mfma_f32_32x32x16_bf16(ah, bl, acc, 0, 0, 0);
    if (ssi + 1 < ns) {
      float4 a4 = {ga.x * silu_f(gz.x), ga.y * silu_f(gz.y),
                   ga.z * silu_f(gz.z), ga.w * silu_f(gz.w)};
      uint2 hi, lo;
      split_pack(a4, &hi, &lo);
      *(uint2*)&sAh[buf ^ 1][kh][st][off] = hi; *(uint2*)&sAl[buf ^ 1][kh][st][off] = lo;
      split_pack(b4, &hi, &lo);
      *(uint2*)&sBh[buf ^ 1][kh][st][off] = hi; *(uint2*)&sBl[buf ^ 1][kh][st][off] = lo;
    }
    __syncthreads();
  }
  if (g == 1) *(f32x16*)&sRed[(wq * 64 + lane) << 4] = acc;
  __syncthreads();
  if (g == 0) {
    f32x16 o = *(f32x16*)&sRed[(wq * 64 + lane) << 4];
#pragma unroll
    for (int i = 0; i < 16; ++i) acc[i] += o[i];
    int col = lane & 31, rq = lane >> 5;
    float* Cw = Cb + (size_t)(bm * 64 + wr * 32) * N + bn * 64 + wc * 32 + col;
#pragma unroll
    for (int rg = 0; rg < 16; ++rg) {
      int row = (rg & 3) + ((rg >> 2) << 3) + (rq << 2);
      Cw[(size_t)row * N] = acc[rg];
    }
  }
}

// --------------- GEMM with fused add+rmsnorm prologue on A -----------------
// A_logical = rms(res_in + sum(parts of Hid)) * nw.  M=512, K=Kc=512, z=0.
// Block bn==0 also writes the un-normalized residual to res_out (ping-pong
// buffer: no reader of res_out exists inside this kernel -> no race).
// A-tile is held fully in registers (rv[16], statically indexed).
__global__ __launch_bounds__(512) void gemm_an_k(const float* __restrict__ Hid,
                                                 int parts,
                                                 const float* __restrict__ res_in,
                                                 float* __restrict__ res_out,
                                                 const float* __restrict__ nw,
                                                 const float* __restrict__ B,
                                                 float* __restrict__ C, int N) {
  __shared__ alignas(16) ushort sAh[2][2][2][512];
  __shared__ alignas(16) ushort sAl[2][2][2][512];
  __shared__ alignas(16) ushort sBh[2][2][2][512];
  __shared__ alignas(16) ushort sBl[2][2][2][512];
  __shared__ alignas(64) float sRed[4096];
  int t = threadIdx.x;
  int bn = blockIdx.x, bm = blockIdx.y;
  const float* Bb = B + (size_t)bn * 64 * 512;
  int r = t >> 3, kc = (t & 7) << 2;
  int row = bm * 64 + r;
  int kh = kc >> 4, kc16 = kc & 15;
  int st = r >> 5, m = r & 31;
  int off = ((kc16 >> 3) << 8) + (m << 3) + (kc16 & 7);
  int w = t >> 6, lane = t & 63;
  int g = w >> 2, wq = w & 3;
  int wr = wq >> 1, wc = wq & 1;

  // ---- prologue: residual accumulate + rms scale, all in registers ----
  float4 rv[16];
  float ss = 0.f;
  {
    const float* rp = res_in + (size_t)row * 512 + kc;
    const float* hp = Hid + (size_t)row * 512 + kc;
#pragma unroll
    for (int j = 0; j < 16; ++j) {
      float4 v = *(const float4*)&rp[j * 32];
      for (int p = 0; p < parts; ++p) {
        float4 h = *(const float4*)&hp[(size_t)p * 262144 + j * 32];
        v.x += h.x; v.y += h.y; v.z += h.z; v.w += h.w;
      }
      rv[j] = v;
      ss += v.x * v.x + v.y * v.y + v.z * v.z + v.w * v.w;
    }
  }
  if (bn == 0) {
    float* ro = res_out + (size_t)row * 512 + kc;
#pragma unroll
    for (int j = 0; j < 16; ++j) *(float4*)&ro[j * 32] = rv[j];
  }
  // 8 lanes (xor 1,2,4) share one row -> full 512-col sum of squares
  ss += __shfl_xor(ss, 1, 64);
  ss += __shfl_xor(ss, 2, 64);
  ss += __shfl_xor(ss, 4, 64);
  float scale = rsqrtf(ss * (1.0f / 512.0f) + 1e-5f);
#pragma unroll
  for (int j = 0; j < 16; ++j) {
    float4 wv = *(const float4*)&nw[kc + j * 32];
    rv[j].x *= scale * wv.x; rv[j].y *= scale * wv.y;
    rv[j].z *= scale * wv.z; rv[j].w *= scale * wv.w;
  }

  f32x16 acc;
#pragma unroll
  for (int i = 0; i < 16; ++i) acc[i] = 0.f;

  float4 b4 = *(const float4*)&Bb[(size_t)r * 512 + kc];
  {
    uint2 hi, lo;
    split_pack(rv[0], &hi, &lo);
    *(uint2*)&sAh[0][kh][st][off] = hi; *(uint2*)&sAl[0][kh][st][off] = lo;
    split_pack(b4, &hi, &lo);
    *(uint2*)&sBh[0][kh][st][off] = hi; *(uint2*)&sBl[0][kh][st][off] = lo;
  }
  __syncthreads();
#pragma unroll
  for (int ssi = 0; ssi < 16; ++ssi) {
    int buf = ssi & 1;
    if (ssi + 1 < 16)
      b4 = *(const float4*)&Bb[(size_t)r * 512 + (ssi + 1) * 32 + kc];
    bf16x8 ah = *(bf16x8*)&sAh[buf][g][wr][lane << 3];
    bf16x8 al = *(bf16x8*)&sAl[buf][g][wr][lane << 3];
    bf16x8 bh = *(bf16x8*)&sBh[buf][g][wc][lane << 3];
    bf16x8 bl = *(bf16x8*)&sBl[buf][g][wc][lane << 3];
    acc = __builtin_amdgcn_mfma_f32_32x32x16_bf16(ah, bh, acc, 0, 0, 0);
    acc = __builtin_amdgcn_mfma_f32_32x32x16_bf16(al, bh, acc, 0, 0, 0);
    acc = __builtin_amdgcn_mfma_f32_32x32x16_bf16(ah, bl, acc, 0, 0, 0);
    if (ssi + 1 < 16) {
      uint2 hi, lo;
      split_pack(rv[ssi + 1], &hi, &lo);
      *(uint2*)&sAh[buf ^ 1][kh][st][off] = hi; *(uint2*)&sAl[buf ^ 1][kh][st][off] = lo;
      split_pack(b4, &hi, &lo);
      *(uint2*)&sBh[buf ^ 1][kh][st][off] = hi; *(uint2*)&sBl[buf ^ 1][kh][st][off] = lo;
    }
    __syncthreads();
  }
  if (g == 1) *(f32x16*)&sRed[(wq * 64 + lane) << 4] = acc;
  __syncthreads();
  if (g == 0) {
    f32x16 o = *(f32x16*)&sRed[(wq * 64 + lane) << 4];
#pragma unroll
    for (int i = 0; i < 16; ++i) acc[i] += o[i];
    int col = lane & 31, rq = lane >> 5;
    float* Cw = C + (size_t)(bm * 64 + wr * 32) * N + bn * 64 + wc * 32 + col;
#pragma unroll
    for (int rg = 0; rg < 16; ++rg) {
      int row2 = (rg & 3) + ((rg >> 2) << 3) + (rq << 2);
      Cw[(size_t)row2 * N] = acc[rg];
    }
  }
}

// --------------------------- patch mean, two stage -------------------------
__global__ void patch_part_k(const float* __restrict__ img, float* __restrict__ pmp) {
  int blk = blockIdx.x;
  int bl = blk / 14, hb = blk % 14;
  int t = threadIdx.x;                 // = c*64 + hi*4 + wi4
  int c = t >> 6, hi = (t >> 2) & 15, wi4 = t & 3;
  const float* base = img + (size_t)bl * 3 * 50176 + (size_t)c * 50176 +
                      (size_t)(hb * 16 + hi) * 224 + wi4 * 4;
  float4 s = {0.f, 0.f, 0.f, 0.f};
#pragma unroll
  for (int wb = 0; wb < 14; ++wb) {
    float4 v = *(const float4*)&base[wb * 16];
    s.x += v.x; s.y += v.y; s.z += v.z; s.w += v.w;
  }
  ((float4*)(pmp + (size_t)blk * 768))[t] = s;
}

__global__ void patch_red_k(const float* __restrict__ pmp, float* __restrict__ meanp) {
  int bl = blockIdx.x;
  int t = threadIdx.x;
  float4 s = {0.f, 0.f, 0.f, 0.f};
  for (int hb = 0; hb < 14; ++hb) {
    float4 v = ((const float4*)(pmp + (size_t)(bl * 14 + hb) * 768))[t];
    s.x += v.x; s.y += v.y; s.z += v.z; s.w += v.w;
  }
  const float inv = 1.0f / 196.0f;
  float4 o = {s.x * inv, s.y * inv, s.z * inv, s.w * inv};
  ((float4*)(meanp + (size_t)bl * 768))[t] = o;
}

// --------------------------- tokenize (scatter) ----------------------------
__global__ void tokenize_k(const float* __restrict__ imgp,
                           const float* __restrict__ states,
                           const float* __restrict__ actions,
                           const float* __restrict__ pb,
                           const float* __restrict__ sw, const float* __restrict__ sb,
                           const float* __restrict__ aw, const float* __restrict__ ab,
                           float* __restrict__ hidden, float* __restrict__ residual) {
  int tok = blockIdx.x;
  int t = threadIdx.x;
  int j = tok & 3;
  int bl = tok >> 2;
  int o0 = t * 4;
  float out[4];
  if (j == 0) {
    float4 a = ((const float4*)pb)[t];
    const float* ip = imgp + (size_t)bl * 512;
#pragma unroll
    for (int p = 0; p < 8; ++p) {
      float4 v = ((const float4*)(ip + (size_t)p * 65536))[t];
      a.x += v.x; a.y += v.y; a.z += v.z; a.w += v.w;
    }
    out[0] = a.x; out[1] = a.y; out[2] = a.z; out[3] = a.w;
  } else if (j == 1) {
    const float* sv = states + (size_t)bl * 21;
#pragma unroll
    for (int i = 0; i < 4; ++i) {
      int o = o0 + i;
      float acc = sb[o];
      for (int k = 0; k < 7; ++k) acc += sw[o * 7 + k] * sv[k];
      out[i] = acc;
    }
  } else {
    const float* av = actions + ((size_t)bl * 3 + (j - 2)) * 4;
#pragma unroll
    for (int i = 0; i < 4; ++i) {
      int o = o0 + i;
      float acc = ab[o];
      for (int k = 0; k < 4; ++k) acc += aw[o * 4 + k] * av[k];
      out[i] = acc;
    }
  }
  float4 ov = {out[0], out[1], out[2], out[3]};
  ((float4*)(hidden + (size_t)tok * 512))[t] = ov;
  float4 z4 = {0.f, 0.f, 0.f, 0.f};
  ((float4*)(residual + (size_t)tok * 512))[t] = z4;
}

// --------------------------- add + rmsnorm (final only) --------------------
__global__ void addnorm_k(const float* __restrict__ hid, int parts,
                          float* __restrict__ res,
                          const float* __restrict__ w, float* __restrict__ xn) {
  int tok = blockIdx.x;
  int t = threadIdx.x;
  float4* r4 = (float4*)(res + (size_t)tok * 512);
  float4 r = r4[t];
  const float4* hp = (const float4*)(hid + (size_t)tok * 512);
  for (int p = 0; p < parts; ++p) {
    float4 h = hp[t];
    r.x += h.x; r.y += h.y; r.z += h.z; r.w += h.w;
    hp += 65536;                       // 512*512 floats between parts
  }
  r4[t] = r;
  float ss = r.x * r.x + r.y * r.y + r.z * r.z + r.w * r.w;
  for (int off = 32; off; off >>= 1) ss += __shfl_down(ss, off, 64);
  __shared__ float s2[2];
  if ((t & 63) == 0) s2[t >> 6] = ss;
  __syncthreads();
  float tot = s2[0] + s2[1];
  float scale = rsqrtf(tot * (1.0f / 512.0f) + 1e-5f);
  float4 wv = ((const float4*)w)[t];
  float4 o = {r.x * scale * wv.x, r.y * scale * wv.y,
              r.z * scale * wv.z, r.w * scale * wv.w};
  ((float4*)(xn + (size_t)tok * 512))[t] = o;
}

// --------------------------- fused conv+silu+xproj+dt ----------------------
__global__ __launch_bounds__(256) void convproj_k(const float* __restrict__ xz,
                                                  const float* __restrict__ cw,
                                                  const float* __restrict__ cb,
                                                  const float* __restrict__ xpw,
                                                  const float* __restrict__ dtw,
                                                  const float* __restrict__ dtbias,
                                                  float* __restrict__ xc,
                                                  float* __restrict__ proj,
                                                  float* __restrict__ dt) {
  int tok = blockIdx.x;
  int t = threadIdx.x;
  int b = tok >> 8, s = tok & 255;
  __shared__ float xr[1024];
  __shared__ float pp[4][64];
  __shared__ float pr[64];
  int d4 = t * 4;
  float4 cw0 = ((const float4*)cw)[d4];
  float4 cw1 = ((const float4*)cw)[d4 + 1];
  float4 cw2 = ((const float4*)cw)[d4 + 2];
  float4 cw3 = ((const float4*)cw)[d4 + 3];
  float acc0 = cb[d4], acc1 = cb[d4 + 1], acc2 = cb[d4 + 2], acc3 = cb[d4 + 3];
  const float* base = xz + (size_t)b * 256 * 2048 + d4;
  const float wk0[4] = {cw0.x, cw0.y, cw0.z, cw0.w};
  const float wk1[4] = {cw1.x, cw1.y, cw1.z, cw1.w};
  const float wk2[4] = {cw2.x, cw2.y, cw2.z, cw2.w};
  const float wk3[4] = {cw3.x, cw3.y, cw3.z, cw3.w};
#pragma unroll
  for (int k = 0; k < 4; ++k) {
    int row = s + k - 3;
    if (row >= 0) {
      float4 v = *(const float4*)&base[(size_t)row * 2048];
      acc0 += wk0[k] * v.x; acc1 += wk1[k] * v.y;
      acc2 += wk2[k] * v.z; acc3 += wk3[k] * v.w;
    }
  }
  float4 xc4 = {silu_f(acc0), silu_f(acc1), silu_f(acc2), silu_f(acc3)};
  ((float4*)(xc + (size_t)tok * 1024))[t] = xc4;
  *(float4*)&xr[d4] = xc4;
  __syncthreads();
  int n = t & 63, q = t >> 6;
  {
    const float* wrow = xpw + (size_t)n * 1024 + q * 256;
    const float* xq = xr + q * 256;
    float acc = 0.f;
    for (int k = 0; k < 256; k += 4)
      acc += wrow[k] * xq[k] + wrow[k + 1] * xq[k + 1] +
             wrow[k + 2] * xq[k + 2] + wrow[k + 3] * xq[k + 3];
    pp[q][n] = acc;
  }
  __syncthreads();
  if (t < 64) {
    float v = pp[0][t] + pp[1][t] + pp[2][t] + pp[3][t];
    pr[t] = v;
    proj[(size_t)tok * 64 + t] = v;
  }
  __syncthreads();
#pragma unroll
  for (int i = 0; i < 4; ++i) {
    int d = t * 4 + i;
    const float* dw = dtw + (size_t)d * 32;
    float a = dtbias[d];
    for (int k = 0; k < 32; ++k) a += dw[k] * pr[k];
    dt[(size_t)tok * 1024 + d] = softplus_f(a);
  }
}

// --------------------------- scan pass 1: chunk pairs ----------------------
// grid (256, 8): x = b*128+dgroup, y = chunk. 128 thr = 8 d x 16 n.
__global__ __launch_bounds__(128) void scan1_k(const float* __restrict__ dt,
                                               const float* __restrict__ proj,
                                               const float* __restrict__ xc,
                                               const float* __restrict__ alog,
                                               float2* __restrict__ pairs) {
  __shared__ float sDt[CS][8];
  __shared__ float sXc[CS][8];
  __shared__ float sB[CS][16];
  int t = threadIdx.x;
  int g = blockIdx.x, c = blockIdx.y;
  int b = g >> 7;
  int d0 = (g & 127) << 3;
  int dl = t >> 4, n = t & 15;
  int d = d0 + dl;
  int s0 = c * CS;
  float A = -expf(alog[d * 16 + n]);
  const float* dtb = dt + ((size_t)b * SEQ + s0) * 1024 + d0;
  const float* xcb = xc + ((size_t)b * SEQ + s0) * 1024 + d0;
  const float* pbp = proj + ((size_t)b * SEQ + s0) * 64 + 32;
  if (t < 64) {
    int li = t >> 1, lc4 = (t & 1) * 4;
    *(float4*)&sDt[li][lc4] = *(const float4*)&dtb[(size_t)li * 1024 + lc4];
    *(float4*)&sXc[li][lc4] = *(const float4*)&xcb[(size_t)li * 1024 + lc4];
  }
  {
    int r = t >> 2, c4 = (t & 3) * 4;
    *(float4*)&sB[r][c4] = *(const float4*)&pbp[(size_t)r * 64 + c4];
  }
  __syncthreads();
  float Ap = 1.f, Bacc = 0.f;
#pragma unroll
  for (int i = 0; i < CS; ++i) {
    float dtv = sDt[i][dl];
    float dA = __expf(dtv * A);
    Bacc = dA * Bacc + dtv * sB[i][n] * sXc[i][dl];
    Ap *= dA;
  }
  pairs[(((size_t)c * 2 + b) * 1024 + d) * 16 + n] = make_float2(Ap, Bacc);
}

// --------------------------- scan pass 2: apply + gate ---------------------
__global__ __launch_bounds__(128) void scan2_k(const float* __restrict__ dt,
                                               const float* __restrict__ proj,
                                               const float* __restrict__ xc,
                                               const float* __restrict__ xz,
                                               const float* __restrict__ alog,
                                               const float* __restrict__ Dp,
                                               const float2* __restrict__ pairs,
                                               float* __restrict__ yz) {
  __shared__ float sDt[CS][8];
  __shared__ float sXc[CS][8];
  __shared__ float sZ[CS][8];
  __shared__ float sBC[CS][32];
  __shared__ float sY[CS][8];
  int t = threadIdx.x;
  int g = blockIdx.x, c = blockIdx.y;
  int b = g >> 7;
  int d0 = (g & 127) << 3;
  int dl = t >> 4, n = t & 15;
  int d = d0 + dl;
  int s0 = c * CS;
  float A = -expf(alog[d * 16 + n]);
  float dp = Dp[d];
  const float* dtb = dt + ((size_t)b * SEQ + s0) * 1024 + d0;
  const float* xcb = xc + ((size_t)b * SEQ + s0) * 1024 + d0;
  const float* zb  = xz + ((size_t)b * SEQ + s0) * 2048 + 1024 + d0;
  const float* pbp = proj + ((size_t)b * SEQ + s0) * 64 + 32;
  float* yb = yz + ((size_t)b * SEQ + s0) * 1024 + d0;
  float h = 0.f;
  for (int cc = 0; cc < c; ++cc) {
    float2 p = pairs[(((size_t)cc * 2 + b) * 1024 + d) * 16 + n];
    h = p.x * h + p.y;
  }
  bool lowh = t < 64;
  int u = lowh ? t : t - 64;
  int li = u >> 1, lc4 = (u & 1) * 4;
  if (lowh) {
    *(float4*)&sDt[li][lc4] = *(const float4*)&dtb[(size_t)li * 1024 + lc4];
    *(float4*)&sXc[li][lc4] = *(const float4*)&xcb[(size_t)li * 1024 + lc4];
  } else {
    *(float4*)&sZ[li][lc4] = *(const float4*)&zb[(size_t)li * 2048 + lc4];
  }
  {
    int v0i = t >> 3, v0c = (t & 7) * 4;
    int v1i = (t + 128) >> 3, v1c = ((t + 128) & 7) * 4;
    *(float4*)&sBC[v0i][v0c] = *(const float4*)&pbp[(size_t)v0i * 64 + v0c];
    *(float4*)&sBC[v1i][v1c] = *(const float4*)&pbp[(size_t)v1i * 64 + v1c];
  }
  __syncthreads();
#pragma unroll
  for (int i = 0; i < CS; ++i) {
    float dtv = sDt[i][dl];
    float xcv = sXc[i][dl];
    float dA = __expf(dtv * A);
    h = dA * h + dtv * sBC[i][n] * xcv;
    float yc = h * sBC[i][16 + n];
    yc += __shfl_xor(yc, 1, 64);
    yc += __shfl_xor(yc, 2, 64);
    yc += __shfl_xor(yc, 4, 64);
    yc += __shfl_xor(yc, 8, 64);
    if (n == 0) sY[i][dl] = (yc + dp * xcv) * silu_f(sZ[i][dl]);
  }
  __syncthreads();
  if (lowh)
    *(float4*)&yb[(size_t)li * 1024 + lc4] = *(const float4*)&sY[li][lc4];
}

// --------------------------- head + |diff| ---------------------------------
__global__ void head_k(const float* __restrict__ hf, const float* __restrict__ hw,
                       const float* __restrict__ hb, const float* __restrict__ labels,
                       float* __restrict__ preds, float* __restrict__ labs) {
  int blk = blockIdx.x;
  int j = blk % 3;
  int l = (blk / 3) % 64;
  int b = blk / 192;
  int row = b * 256 + l * 4 + 1 + j;
  int t = threadIdx.x;
  const float* x = hf + (size_t)row * 512;
  float acc[4] = {0.f, 0.f, 0.f, 0.f};
  for (int k = t; k < 512; k += 64) {
    float xv = x[k];
#pragma unroll
    for (int a = 0; a < 4; ++a) acc[a] += xv * hw[a * 512 + k];
  }
  for (int off = 32; off; off >>= 1) {
#pragma unroll
    for (int a = 0; a < 4; ++a) acc[a] += __shfl_down(acc[a], off, 64);
  }
  if (t == 0) {
    const float* lab = labels + (size_t)blk * 4;
    float sd = 0.f;
#pragma unroll
    for (int a = 0; a < 4; ++a) {
      float p = acc[a] + hb[a];
      preds[(size_t)blk * 4 + a] = p;
      sd += fabsf(p - lab[a]);
    }
    labs[blk] = sd;
  }
}

// --------------------------- loss ------------------------------------------
__global__ void loss_k(const float* __restrict__ labs, const int* __restrict__ seqlen,
                       float* __restrict__ out) {
  int t = threadIdx.x;
  int b = t >> 6, l = t & 63;
  float la = (labs[(b * 64 + l) * 3] + labs[(b * 64 + l) * 3 + 1] +
              labs[(b * 64 + l) * 3 + 2]) * (1.0f / 12.0f);
  float m = (l < seqlen[b]) ? 1.f : 0.f;
  float v = la * m;
  for (int off = 32; off; off >>= 1) {
    v += __shfl_down(v, off, 64);
    m += __shfl_down(m, off, 64);
  }
  __shared__ float sb_[2];
  if ((t & 63) == 0) sb_[b] = v / fmaxf(m, 1.0f);
  __syncthreads();
  if (t == 0) out[0] = 0.5f * (sb_[0] + sb_[1]);
}

// ---------------------------------------------------------------------------
extern "C" void kernel_launch(void* const* d_in, const int* in_sizes, int n_in,
                              void* d_out, int out_size, void* d_ws, size_t ws_size,
                              hipStream_t stream) {
  const float* images     = (const float*)d_in[0];
  const int*   seq_length = (const int*)d_in[1];
  const float* states     = (const float*)d_in[2];
  const float* actions    = (const float*)d_in[3];
  const float* labels     = (const float*)d_in[4];
  const float* patch_w    = (const float*)d_in[5];
  const float* patch_b    = (const float*)d_in[6];
  const float* state_w    = (const float*)d_in[7];
  const float* state_b    = (const float*)d_in[8];
  const float* act_w      = (const float*)d_in[9];
  const float* act_b      = (const float*)d_in[10];
  const float* norm1_w    = (const float*)d_in[11];
  const float* in_proj_w  = (const float*)d_in[12];
  const float* conv_w     = (const float*)d_in[13];
  const float* conv_b     = (const float*)d_in[14];
  const float* x_proj_w   = (const float*)d_in[15];
  const float* dt_w       = (const float*)d_in[16];
  const float* dt_b       = (const float*)d_in[17];
  const float* A_log      = (const float*)d_in[18];
  const float* Dp         = (const float*)d_in[19];
  const float* out_proj_w = (const float*)d_in[20];
  const float* norm2_w    = (const float*)d_in[21];
  const float* fc1_w      = (const float*)d_in[22];
  const float* fc2_w      = (const float*)d_in[23];
  const float* norm_f_w   = (const float*)d_in[24];
  const float* head_w     = (const float*)d_in[25];
  const float* head_b     = (const float*)d_in[26];

  float* out = (float*)d_out;

  float* ws = (float*)d_ws;
  float* meanp    = ws; ws += 98304;     // (128, 768)
  float* hidden   = ws; ws += 262144;    // (512, 512)
  float* residual = ws; ws += 262144;    // ping
  float* residual2= ws; ws += 262144;    // pong
  float* xn       = ws; ws += 262144;
  float* xz       = ws; ws += 1048576;   // (512, 2048)
  float* xc       = ws; ws += 524288;    // (512, 1024)
  float* proj     = ws; ws += 32768;     // (512, 64)
  float* dtbuf    = ws; ws += 524288;    // (512, 1024)
  float* yz       = ws; ws += 524288;    // (512, 1024)
  float* labs     = ws; ws += 384;
  float* cpart    = ws; ws += 1048576;   // split-K partials (max 4x512x512)
  float* pmp      = ws; ws += 1376256;   // (1792, 768) patch partials
  float2* pairs   = (float2*)ws; ws += 524288;  // (8,2,1024,16) float2

  hipLaunchKernelGGL(patch_part_k, dim3(1792), dim3(192), 0, stream, images, pmp);
  hipLaunchKernelGGL(patch_red_k, dim3(128), dim3(192), 0, stream, pmp, meanp);
  hipLaunchKernelGGL(gemm_bs_k, dim3(8, 2, 8), dim3(512), 0, stream,
                     meanp, patch_w, cpart, 128, 512, 768, 96);
  hipLaunchKernelGGL(tokenize_k, dim3(512), dim3(128), 0, stream, cpart, states, actions,
                     patch_b, state_w, state_b, act_w, act_b, hidden, residual);

  for (int i = 0; i < 8; ++i) {
    const float* n1 = norm1_w + i * 512;
    const float* ipw = in_proj_w + (size_t)i * 2048 * 512;
    const float* cw = conv_w + (size_t)i * 4096;
    const float* cb = conv_b + (size_t)i * 1024;
    const float* xpw = x_proj_w + (size_t)i * 65536;
    const float* dtw = dt_w + (size_t)i * 32768;
    const float* dtbias = dt_b + (size_t)i * 1024;
    const float* al = A_log + (size_t)i * 16384;
    const float* dpp = Dp + (size_t)i * 1024;
    const float* opw = out_proj_w + (size_t)i * 524288;
    const float* n2 = norm2_w + i * 512;
    const float* f1 = fc1_w + (size_t)i * 1048576;
    const float* f2 = fc2_w + (size_t)i * 524288;

    // residual ping-pong: in_proj reads residual -> writes residual2,
    // fc1 reads residual2 -> writes residual.
    const float* hid_in = (i == 0) ? hidden : cpart;
    int parts = (i == 0) ? 1 : 4;
    hipLaunchKernelGGL(gemm_an_k, dim3(32, 8), dim3(512), 0, stream,
                       hid_in, parts, residual, residual2, n1, ipw, xz, 2048);
    hipLaunchKernelGGL(convproj_k, dim3(512), dim3(256), 0, stream,
                       xz, cw, cb, xpw, dtw, dtbias, xc, proj, dtbuf);
    hipLaunchKernelGGL(scan1_k, dim3(256, 8), dim3(128), 0, stream,
                       dtbuf, proj, xc, al, pairs);
    hipLaunchKernelGGL(scan2_k, dim3(256, 8), dim3(128), 0, stream,
                       dtbuf, proj, xc, xz, al, dpp, pairs, yz);
    hipLaunchKernelGGL(gemm_bs_k, dim3(8, 8, 4), dim3(512), 0, stream,
                       yz, opw, cpart, 512, 512, 1024, 256);
    hipLaunchKernelGGL(gemm_an_k, dim3(32, 8), dim3(512), 0, stream,
                       cpart, 4, residual2, residual, n2, f1, xz, 2048);
    hipLaunchKernelGGL(gemm_glu_k, dim3(8, 8, 4), dim3(512), 0, stream,
                       xz, f2, cpart, 512, 512, 1024, 256);
  }

  hipLaunchKernelGGL(addnorm_k, dim3(512), dim3(128), 0, stream,
                     cpart, 4, residual, norm_f_w, xn);
  hipLaunchKernelGGL(head_k, dim3(384), dim3(64), 0, stream, xn, head_w, head_b, labels,
                     out + 1, labs);
  hipLaunchKernelGGL(loss_k, dim3(1), dim3(128), 0, stream, labs, seq_length, out);
}

// Round 2
// 1117.064 us; speedup vs baseline: 1.2184x; 1.2184x over previous
//
#include <hip/hip_runtime.h>

// ---------------------------------------------------------------------------
// DVGMamba forward. Round 8: round-6 structure (verified 1174.8us) +
//   (a) BK=32 GEMM K-loop: 6 MFMA + 8 ds_read per barrier, 2x prefetch depth
//       (accumulation order identical to round-6 -> same numerics)
//   (b) fused single-kernel two-pass chunked scan (replaces scan1+scan2,
//       kills the pairs global round-trip)
// Round-7 gemm_an fusion REVERTED: 32x-replicated residual+norm prologue
// added ~165MB L2 traffic per call (x16) -> +186us regression.
// b=2, l=64, S=256 tokens, D=512, DIN=1024, DS=16, DTR=32, K=4, Layers=8
// ---------------------------------------------------------------------------

#define NTOK 512
#define SEQ  256
#define CS   32     // scan chunk size
#define NC   8      // chunks

typedef __attribute__((ext_vector_type(8))) short bf16x8;
typedef __attribute__((ext_vector_type(16))) float f32x16;

__device__ __forceinline__ float silu_f(float x) { return x / (1.0f + expf(-x)); }
__device__ __forceinline__ float softplus_f(float x) {
  return (x > 20.0f) ? x : log1pf(expf(x));
}

// split fp32 -> (hi bf16, lo bf16) by truncation; packed 2x bf16 per dword
__device__ __forceinline__ void split_pack(float4 v, uint2* hi, uint2* lo) {
  uint ux = __float_as_uint(v.x), uy = __float_as_uint(v.y);
  uint uz = __float_as_uint(v.z), uw = __float_as_uint(v.w);
  hi->x = (ux >> 16) | (uy & 0xffff0000u);
  hi->y = (uz >> 16) | (uw & 0xffff0000u);
  float lx = v.x - __uint_as_float(ux & 0xffff0000u);
  float ly = v.y - __uint_as_float(uy & 0xffff0000u);
  float lz = v.z - __uint_as_float(uz & 0xffff0000u);
  float lw = v.w - __uint_as_float(uw & 0xffff0000u);
  lo->x = (__float_as_uint(lx) >> 16) | (__float_as_uint(ly) & 0xffff0000u);
  lo->y = (__float_as_uint(lz) >> 16) | (__float_as_uint(lw) & 0xffff0000u);
}

// --------------------------- split-bf16 MFMA NT GEMM -----------------------
// 256 threads = 4 waves, 64x64 tile, one 32x32 quadrant per wave.
// BK=32 superstep: two 16-K sub-steps per barrier.
__global__ __launch_bounds__(256) void gemm_bs_k(const float* __restrict__ A,
                                                 const float* __restrict__ B,
                                                 float* __restrict__ C,
                                                 int M, int N, int K, int Kc) {
  __shared__ alignas(16) ushort sAh[2][2][2][512];   // [dbuf][ks][st][.]
  __shared__ alignas(16) ushort sAl[2][2][2][512];
  __shared__ alignas(16) ushort sBh[2][2][2][512];
  __shared__ alignas(16) ushort sBl[2][2][2][512];
  int t = threadIdx.x;
  int bn = blockIdx.x, bm = blockIdx.y, z = blockIdx.z;
  const float* Ab = A + (size_t)bm * 64 * K + (size_t)z * Kc;
  const float* Bb = B + (size_t)bn * 64 * K + (size_t)z * Kc;
  float* Cb = C + (size_t)z * M * N;
  int r = t >> 2, kc = (t & 3) << 2;     // 64 rows x (k 0..15), +16 for ks=1
  int st = r >> 5, m = r & 31;
  int off = ((kc >> 3) << 8) + (m << 3) + (kc & 7);
  int w = t >> 6, lane = t & 63;
  int wr = w >> 1, wc = w & 1;

  f32x16 acc;
#pragma unroll
  for (int i = 0; i < 16; ++i) acc[i] = 0.f;

  int ns = Kc >> 5;
  const float* Ar = Ab + (size_t)r * K + kc;
  const float* Br = Bb + (size_t)r * K + kc;
  float4 a0 = *(const float4*)&Ar[0];
  float4 a1 = *(const float4*)&Ar[16];
  float4 b0 = *(const float4*)&Br[0];
  float4 b1 = *(const float4*)&Br[16];
  {
    uint2 hi, lo;
    split_pack(a0, &hi, &lo);
    *(uint2*)&sAh[0][0][st][off] = hi; *(uint2*)&sAl[0][0][st][off] = lo;
    split_pack(a1, &hi, &lo);
    *(uint2*)&sAh[0][1][st][off] = hi; *(uint2*)&sAl[0][1][st][off] = lo;
    split_pack(b0, &hi, &lo);
    *(uint2*)&sBh[0][0][st][off] = hi; *(uint2*)&sBl[0][0][st][off] = lo;
    split_pack(b1, &hi, &lo);
    *(uint2*)&sBh[0][1][st][off] = hi; *(uint2*)&sBl[0][1][st][off] = lo;
  }
  __syncthreads();
  for (int ssi = 0; ssi < ns; ++ssi) {
    int buf = ssi & 1;
    if (ssi + 1 < ns) {
      a0 = *(const float4*)&Ar[(ssi + 1) * 32];
      a1 = *(const float4*)&Ar[(ssi + 1) * 32 + 16];
      b0 = *(const float4*)&Br[(ssi + 1) * 32];
      b1 = *(const float4*)&Br[(ssi + 1) * 32 + 16];
    }
    bf16x8 ah = *(bf16x8*)&sAh[buf][0][wr][lane << 3];
    bf16x8 al = *(bf16x8*)&sAl[buf][0][wr][lane << 3];
    bf16x8 bh = *(bf16x8*)&sBh[buf][0][wc][lane << 3];
    bf16x8 bl = *(bf16x8*)&sBl[buf][0][wc][lane << 3];
    acc = __builtin_amdgcn_mfma_f32_32x32x16_bf16(ah, bh, acc, 0, 0, 0);
    acc = __builtin_amdgcn_mfma_f32_32x32x16_bf16(al, bh, acc, 0, 0, 0);
    acc = __builtin_amdgcn_mfma_f32_32x32x16_bf16(ah, bl, acc, 0, 0, 0);
    bf16x8 ah1 = *(bf16x8*)&sAh[buf][1][wr][lane << 3];
    bf16x8 al1 = *(bf16x8*)&sAl[buf][1][wr][lane << 3];
    bf16x8 bh1 = *(bf16x8*)&sBh[buf][1][wc][lane << 3];
    bf16x8 bl1 = *(bf16x8*)&sBl[buf][1][wc][lane << 3];
    acc = __builtin_amdgcn_mfma_f32_32x32x16_bf16(ah1, bh1, acc, 0, 0, 0);
    acc = __builtin_amdgcn_mfma_f32_32x32x16_bf16(al1, bh1, acc, 0, 0, 0);
    acc = __builtin_amdgcn_mfma_f32_32x32x16_bf16(ah1, bl1, acc, 0, 0, 0);
    if (ssi + 1 < ns) {
      uint2 hi, lo;
      split_pack(a0, &hi, &lo);
      *(uint2*)&sAh[buf ^ 1][0][st][off] = hi; *(uint2*)&sAl[buf ^ 1][0][st][off] = lo;
      split_pack(a1, &hi, &lo);
      *(uint2*)&sAh[buf ^ 1][1][st][off] = hi; *(uint2*)&sAl[buf ^ 1][1][st][off] = lo;
      split_pack(b0, &hi, &lo);
      *(uint2*)&sBh[buf ^ 1][0][st][off] = hi; *(uint2*)&sBl[buf ^ 1][0][st][off] = lo;
      split_pack(b1, &hi, &lo);
      *(uint2*)&sBh[buf ^ 1][1][st][off] = hi; *(uint2*)&sBl[buf ^ 1][1][st][off] = lo;
    }
    __syncthreads();
  }
  int col = lane & 31, rq = lane >> 5;
  float* Cw = Cb + (size_t)(bm * 64 + wr * 32) * N + bn * 64 + wc * 32 + col;
#pragma unroll
  for (int rg = 0; rg < 16; ++rg) {
    int row = (rg & 3) + ((rg >> 2) << 3) + (rq << 2);
    Cw[(size_t)row * N] = acc[rg];
  }
}

// --------------------------- GEMM with fused GLU on A ----------------------
// A_logical[r,k] = g[r*2048+k] * silu(g[r*2048+1024+k]); K = 1024. BK=32.
__global__ __launch_bounds__(256) void gemm_glu_k(const float* __restrict__ G,
                                                  const float* __restrict__ B,
                                                  float* __restrict__ C,
                                                  int M, int N, int K, int Kc) {
  __shared__ alignas(16) ushort sAh[2][2][2][512];
  __shared__ alignas(16) ushort sAl[2][2][2][512];
  __shared__ alignas(16) ushort sBh[2][2][2][512];
  __shared__ alignas(16) ushort sBl[2][2][2][512];
  int t = threadIdx.x;
  int bn = blockIdx.x, bm = blockIdx.y, z = blockIdx.z;
  const float* Gb = G + (size_t)bm * 64 * 2048 + (size_t)z * Kc;
  const float* Bb = B + (size_t)bn * 64 * K + (size_t)z * Kc;
  float* Cb = C + (size_t)z * M * N;
  int r = t >> 2, kc = (t & 3) << 2;
  int st = r >> 5, m = r & 31;
  int off = ((kc >> 3) << 8) + (m << 3) + (kc & 7);
  int w = t >> 6, lane = t & 63;
  int wr = w >> 1, wc = w & 1;

  f32x16 acc;
#pragma unroll
  for (int i = 0; i < 16; ++i) acc[i] = 0.f;

  int ns = Kc >> 5;
  const float* gr = Gb + (size_t)r * 2048 + kc;
  const float* Br = Bb + (size_t)r * K + kc;
  float4 ga0 = *(const float4*)&gr[0];
  float4 gz0 = *(const float4*)&gr[1024];
  float4 ga1 = *(const float4*)&gr[16];
  float4 gz1 = *(const float4*)&gr[1040];
  float4 b0 = *(const float4*)&Br[0];
  float4 b1 = *(const float4*)&Br[16];
  {
    float4 a0 = {ga0.x * silu_f(gz0.x), ga0.y * silu_f(gz0.y),
                 ga0.z * silu_f(gz0.z), ga0.w * silu_f(gz0.w)};
    float4 a1 = {ga1.x * silu_f(gz1.x), ga1.y * silu_f(gz1.y),
                 ga1.z * silu_f(gz1.z), ga1.w * silu_f(gz1.w)};
    uint2 hi, lo;
    split_pack(a0, &hi, &lo);
    *(uint2*)&sAh[0][0][st][off] = hi; *(uint2*)&sAl[0][0][st][off] = lo;
    split_pack(a1, &hi, &lo);
    *(uint2*)&sAh[0][1][st][off] = hi; *(uint2*)&sAl[0][1][st][off] = lo;
    split_pack(b0, &hi, &lo);
    *(uint2*)&sBh[0][0][st][off] = hi; *(uint2*)&sBl[0][0][st][off] = lo;
    split_pack(b1, &hi, &lo);
    *(uint2*)&sBh[0][1][st][off] = hi; *(uint2*)&sBl[0][1][st][off] = lo;
  }
  __syncthreads();
  for (int ssi = 0; ssi < ns; ++ssi) {
    int buf = ssi & 1;
    if (ssi + 1 < ns) {
      ga0 = *(const float4*)&gr[(ssi + 1) * 32];
      gz0 = *(const float4*)&gr[1024 + (ssi + 1) * 32];
      ga1 = *(const float4*)&gr[(ssi + 1) * 32 + 16];
      gz1 = *(const float4*)&gr[1040 + (ssi + 1) * 32];
      b0 = *(const float4*)&Br[(ssi + 1) * 32];
      b1 = *(const float4*)&Br[(ssi + 1) * 32 + 16];
    }
    bf16x8 ah = *(bf16x8*)&sAh[buf][0][wr][lane << 3];
    bf16x8 al = *(bf16x8*)&sAl[buf][0][wr][lane << 3];
    bf16x8 bh = *(bf16x8*)&sBh[buf][0][wc][lane << 3];
    bf16x8 bl = *(bf16x8*)&sBl[buf][0][wc][lane << 3];
    acc = __builtin_amdgcn_mfma_f32_32x32x16_bf16(ah, bh, acc, 0, 0, 0);
    acc = __builtin_amdgcn_mfma_f32_32x32x16_bf16(al, bh, acc, 0, 0, 0);
    acc = __builtin_amdgcn_mfma_f32_32x32x16_bf16(ah, bl, acc, 0, 0, 0);
    bf16x8 ah1 = *(bf16x8*)&sAh[buf][1][wr][lane << 3];
    bf16x8 al1 = *(bf16x8*)&sAl[buf][1][wr][lane << 3];
    bf16x8 bh1 = *(bf16x8*)&sBh[buf][1][wc][lane << 3];
    bf16x8 bl1 = *(bf16x8*)&sBl[buf][1][wc][lane << 3];
    acc = __builtin_amdgcn_mfma_f32_32x32x16_bf16(ah1, bh1, acc, 0, 0, 0);
    acc = __builtin_amdgcn_mfma_f32_32x32x16_bf16(al1, bh1, acc, 0, 0, 0);
    acc = __builtin_amdgcn_mfma_f32_32x32x16_bf16(ah1, bl1, acc, 0, 0, 0);
    if (ssi + 1 < ns) {
      float4 a0 = {ga0.x * silu_f(gz0.x), ga0.y * silu_f(gz0.y),
                   ga0.z * silu_f(gz0.z), ga0.w * silu_f(gz0.w)};
      float4 a1 = {ga1.x * silu_f(gz1.x), ga1.y * silu_f(gz1.y),
                   ga1.z * silu_f(gz1.z), ga1.w * silu_f(gz1.w)};
      uint2 hi, lo;
      split_pack(a0, &hi, &lo);
      *(uint2*)&sAh[buf ^ 1][0][st][off] = hi; *(uint2*)&sAl[buf ^ 1][0][st][off] = lo;
      split_pack(a1, &hi, &lo);
      *(uint2*)&sAh[buf ^ 1][1][st][off] = hi; *(uint2*)&sAl[buf ^ 1][1][st][off] = lo;
      split_pack(b0, &hi, &lo);
      *(uint2*)&sBh[buf ^ 1][0][st][off] = hi; *(uint2*)&sBl[buf ^ 1][0][st][off] = lo;
      split_pack(b1, &hi, &lo);
      *(uint2*)&sBh[buf ^ 1][1][st][off] = hi; *(uint2*)&sBl[buf ^ 1][1][st][off] = lo;
    }
    __syncthreads();
  }
  int col = lane & 31, rq = lane >> 5;
  float* Cw = Cb + (size_t)(bm * 64 + wr * 32) * N + bn * 64 + wc * 32 + col;
#pragma unroll
  for (int rg = 0; rg < 16; ++rg) {
    int row = (rg & 3) + ((rg >> 2) << 3) + (rq << 2);
    Cw[(size_t)row * N] = acc[rg];
  }
}

// --------------------------- patch mean, two stage -------------------------
__global__ void patch_part_k(const float* __restrict__ img, float* __restrict__ pmp) {
  int blk = blockIdx.x;
  int bl = blk / 14, hb = blk % 14;
  int t = threadIdx.x;                 // = c*64 + hi*4 + wi4
  int c = t >> 6, hi = (t >> 2) & 15, wi4 = t & 3;
  const float* base = img + (size_t)bl * 3 * 50176 + (size_t)c * 50176 +
                      (size_t)(hb * 16 + hi) * 224 + wi4 * 4;
  float4 s = {0.f, 0.f, 0.f, 0.f};
#pragma unroll
  for (int wb = 0; wb < 14; ++wb) {
    float4 v = *(const float4*)&base[wb * 16];
    s.x += v.x; s.y += v.y; s.z += v.z; s.w += v.w;
  }
  ((float4*)(pmp + (size_t)blk * 768))[t] = s;
}

__global__ void patch_red_k(const float* __restrict__ pmp, float* __restrict__ meanp) {
  int bl = blockIdx.x;
  int t = threadIdx.x;
  float4 s = {0.f, 0.f, 0.f, 0.f};
  for (int hb = 0; hb < 14; ++hb) {
    float4 v = ((const float4*)(pmp + (size_t)(bl * 14 + hb) * 768))[t];
    s.x += v.x; s.y += v.y; s.z += v.z; s.w += v.w;
  }
  const float inv = 1.0f / 196.0f;
  float4 o = {s.x * inv, s.y * inv, s.z * inv, s.w * inv};
  ((float4*)(meanp + (size_t)bl * 768))[t] = o;
}

// --------------------------- tokenize (scatter) ----------------------------
__global__ void tokenize_k(const float* __restrict__ imgp,
                           const float* __restrict__ states,
                           const float* __restrict__ actions,
                           const float* __restrict__ pb,
                           const float* __restrict__ sw, const float* __restrict__ sb,
                           const float* __restrict__ aw, const float* __restrict__ ab,
                           float* __restrict__ hidden, float* __restrict__ residual) {
  int tok = blockIdx.x;
  int t = threadIdx.x;
  int j = tok & 3;
  int bl = tok >> 2;
  int o0 = t * 4;
  float out[4];
  if (j == 0) {
    float4 a = ((const float4*)pb)[t];
    const float* ip = imgp + (size_t)bl * 512;
#pragma unroll
    for (int p = 0; p < 8; ++p) {
      float4 v = ((const float4*)(ip + (size_t)p * 65536))[t];
      a.x += v.x; a.y += v.y; a.z += v.z; a.w += v.w;
    }
    out[0] = a.x; out[1] = a.y; out[2] = a.z; out[3] = a.w;
  } else if (j == 1) {
    const float* sv = states + (size_t)bl * 21;
#pragma unroll
    for (int i = 0; i < 4; ++i) {
      int o = o0 + i;
      float acc = sb[o];
      for (int k = 0; k < 7; ++k) acc += sw[o * 7 + k] * sv[k];
      out[i] = acc;
    }
  } else {
    const float* av = actions + ((size_t)bl * 3 + (j - 2)) * 4;
#pragma unroll
    for (int i = 0; i < 4; ++i) {
      int o = o0 + i;
      float acc = ab[o];
      for (int k = 0; k < 4; ++k) acc += aw[o * 4 + k] * av[k];
      out[i] = acc;
    }
  }
  float4 ov = {out[0], out[1], out[2], out[3]};
  ((float4*)(hidden + (size_t)tok * 512))[t] = ov;
  float4 z4 = {0.f, 0.f, 0.f, 0.f};
  ((float4*)(residual + (size_t)tok * 512))[t] = z4;
}

// --------------------------- add + rmsnorm ---------------------------------
__global__ void addnorm_k(const float* __restrict__ hid, int parts,
                          float* __restrict__ res,
                          const float* __restrict__ w, float* __restrict__ xn) {
  int tok = blockIdx.x;
  int t = threadIdx.x;
  float4* r4 = (float4*)(res + (size_t)tok * 512);
  float4 r = r4[t];
  const float4* hp = (const float4*)(hid + (size_t)tok * 512);
  for (int p = 0; p < parts; ++p) {
    float4 h = hp[t];
    r.x += h.x; r.y += h.y; r.z += h.z; r.w += h.w;
    hp += 65536;                       // 512*512 floats between parts
  }
  r4[t] = r;
  float ss = r.x * r.x + r.y * r.y + r.z * r.z + r.w * r.w;
  for (int off = 32; off; off >>= 1) ss += __shfl_down(ss, off, 64);
  __shared__ float s2[2];
  if ((t & 63) == 0) s2[t >> 6] = ss;
  __syncthreads();
  float tot = s2[0] + s2[1];
  float scale = rsqrtf(tot * (1.0f / 512.0f) + 1e-5f);
  float4 wv = ((const float4*)w)[t];
  float4 o = {r.x * scale * wv.x, r.y * scale * wv.y,
              r.z * scale * wv.z, r.w * scale * wv.w};
  ((float4*)(xn + (size_t)tok * 512))[t] = o;
}

// --------------------------- fused conv+silu+xproj+dt ----------------------
__global__ __launch_bounds__(256) void convproj_k(const float* __restrict__ xz,
                                                  const float* __restrict__ cw,
                                                  const float* __restrict__ cb,
                                                  const float* __restrict__ xpw,
                                                  const float* __restrict__ dtw,
                                                  const float* __restrict__ dtbias,
                                                  float* __restrict__ xc,
                                                  float* __restrict__ proj,
                                                  float* __restrict__ dt) {
  int tok = blockIdx.x;
  int t = threadIdx.x;
  int b = tok >> 8, s = tok & 255;
  __shared__ float xr[1024];
  __shared__ float pp[4][64];
  __shared__ float pr[64];
  int d4 = t * 4;
  float4 cw0 = ((const float4*)cw)[d4];
  float4 cw1 = ((const float4*)cw)[d4 + 1];
  float4 cw2 = ((const float4*)cw)[d4 + 2];
  float4 cw3 = ((const float4*)cw)[d4 + 3];
  float acc0 = cb[d4], acc1 = cb[d4 + 1], acc2 = cb[d4 + 2], acc3 = cb[d4 + 3];
  const float* base = xz + (size_t)b * 256 * 2048 + d4;
  const float wk0[4] = {cw0.x, cw0.y, cw0.z, cw0.w};
  const float wk1[4] = {cw1.x, cw1.y, cw1.z, cw1.w};
  const float wk2[4] = {cw2.x, cw2.y, cw2.z, cw2.w};
  const float wk3[4] = {cw3.x, cw3.y, cw3.z, cw3.w};
#pragma unroll
  for (int k = 0; k < 4; ++k) {
    int row = s + k - 3;
    if (row >= 0) {
      float4 v = *(const float4*)&base[(size_t)row * 2048];
      acc0 += wk0[k] * v.x; acc1 += wk1[k] * v.y;
      acc2 += wk2[k] * v.z; acc3 += wk3[k] * v.w;
    }
  }
  float4 xc4 = {silu_f(acc0), silu_f(acc1), silu_f(acc2), silu_f(acc3)};
  ((float4*)(xc + (size_t)tok * 1024))[t] = xc4;
  *(float4*)&xr[d4] = xc4;
  __syncthreads();
  int n = t & 63, q = t >> 6;
  {
    const float* wrow = xpw + (size_t)n * 1024 + q * 256;
    const float* xq = xr + q * 256;
    float acc = 0.f;
    for (int k = 0; k < 256; k += 4)
      acc += wrow[k] * xq[k] + wrow[k + 1] * xq[k + 1] +
             wrow[k + 2] * xq[k + 2] + wrow[k + 3] * xq[k + 3];
    pp[q][n] = acc;
  }
  __syncthreads();
  if (t < 64) {
    float v = pp[0][t] + pp[1][t] + pp[2][t] + pp[3][t];
    pr[t] = v;
    proj[(size_t)tok * 64 + t] = v;
  }
  __syncthreads();
#pragma unroll
  for (int i = 0; i < 4; ++i) {
    int d = t * 4 + i;
    const float* dw = dtw + (size_t)d * 32;
    float a = dtbias[d];
    for (int k = 0; k < 32; ++k) a += dw[k] * pr[k];
    dt[(size_t)tok * 1024 + d] = softplus_f(a);
  }
}

// --------------------------- fused two-pass chunked scan -------------------
// grid (512): blockIdx.x = b*256 + dgroup(4 dims). 512 thr = 8 chunks x 4 d
// x 16 n. Pass1: per-chunk (Aprod, Bacc) -> LDS. Prefix in-block. Pass2:
// apply + n-reduce + D-residual + silu(z) gate. All inputs staged once.
__global__ __launch_bounds__(512) void scan_k(const float* __restrict__ dt,
                                              const float* __restrict__ proj,
                                              const float* __restrict__ xc,
                                              const float* __restrict__ xz,
                                              const float* __restrict__ alog,
                                              const float* __restrict__ Dp,
                                              float* __restrict__ yz) {
  __shared__ float sDt[256][4];
  __shared__ float sXc[256][4];
  __shared__ float sZ[256][4];
  __shared__ float sBC[256][32];
  __shared__ float2 sP[8][4][16];
  __shared__ float sY[256][4];
  int t = threadIdx.x;
  int g = blockIdx.x;
  int b = g >> 8;
  int d0 = (g & 255) << 2;
  int c = t >> 6, dl = (t >> 4) & 3, n = t & 15;
  int d = d0 + dl;
  const float* dtb = dt + (size_t)b * 256 * 1024 + d0;
  const float* xcb = xc + (size_t)b * 256 * 1024 + d0;
  const float* zb  = xz + (size_t)b * 256 * 2048 + 1024 + d0;
  const float* pbp = proj + (size_t)b * 256 * 64 + 32;
  float* yb = yz + (size_t)b * 256 * 1024 + d0;

  if (t < 256) {
    *(float4*)&sDt[t][0] = *(const float4*)&dtb[(size_t)t * 1024];
    *(float4*)&sZ[t][0]  = *(const float4*)&zb[(size_t)t * 2048];
  } else {
    int u = t - 256;
    *(float4*)&sXc[u][0] = *(const float4*)&xcb[(size_t)u * 1024];
  }
#pragma unroll
  for (int i = 0; i < 4; ++i) {
    int idx = i * 512 + t;
    int s = idx >> 3, c4 = (idx & 7) << 2;
    *(float4*)&sBC[s][c4] = *(const float4*)&pbp[(size_t)s * 64 + c4];
  }
  float A = -expf(alog[d * 16 + n]);
  float dp = Dp[d];
  __syncthreads();

  // pass 1: per-chunk pair
  float Ap = 1.f, Bacc = 0.f;
#pragma unroll
  for (int i = 0; i < CS; ++i) {
    int s = (c << 5) + i;
    float dtv = sDt[s][dl];
    float dA = __expf(dtv * A);
    Bacc = dA * Bacc + dtv * sBC[s][n] * sXc[s][dl];
    Ap *= dA;
  }
  sP[c][dl][n] = make_float2(Ap, Bacc);
  __syncthreads();

  // prefix over earlier chunks (wave-uniform trip count: wave == chunk)
  float h = 0.f;
  for (int cc = 0; cc < c; ++cc) {
    float2 p = sP[cc][dl][n];
    h = p.x * h + p.y;
  }

  // pass 2: apply + gate
#pragma unroll
  for (int i = 0; i < CS; ++i) {
    int s = (c << 5) + i;
    float dtv = sDt[s][dl];
    float xcv = sXc[s][dl];
    float dA = __expf(dtv * A);
    h = dA * h + dtv * sBC[s][n] * xcv;
    float yc = h * sBC[s][16 + n];
    yc += __shfl_xor(yc, 1, 64);
    yc += __shfl_xor(yc, 2, 64);
    yc += __shfl_xor(yc, 4, 64);
    yc += __shfl_xor(yc, 8, 64);
    if (n == 0) sY[s][dl] = (yc + dp * xcv) * silu_f(sZ[s][dl]);
  }
  __syncthreads();
  if (t < 256)
    *(float4*)&yb[(size_t)t * 1024] = *(const float4*)&sY[t][0];
}

// --------------------------- head + |diff| ---------------------------------
__global__ void head_k(const float* __restrict__ hf, const float* __restrict__ hw,
                       const float* __restrict__ hb, const float* __restrict__ labels,
                       float* __restrict__ preds, float* __restrict__ labs) {
  int blk = blockIdx.x;
  int j = blk % 3;
  int l = (blk / 3) % 64;
  int b = blk / 192;
  int row = b * 256 + l * 4 + 1 + j;
  int t = threadIdx.x;
  const float* x = hf + (size_t)row * 512;
  float acc[4] = {0.f, 0.f, 0.f, 0.f};
  for (int k = t; k < 512; k += 64) {
    float xv = x[k];
#pragma unroll
    for (int a = 0; a < 4; ++a) acc[a] += xv * hw[a * 512 + k];
  }
  for (int off = 32; off; off >>= 1) {
#pragma unroll
    for (int a = 0; a < 4; ++a) acc[a] += __shfl_down(acc[a], off, 64);
  }
  if (t == 0) {
    const float* lab = labels + (size_t)blk * 4;
    float sd = 0.f;
#pragma unroll
    for (int a = 0; a < 4; ++a) {
      float p = acc[a] + hb[a];
      preds[(size_t)blk * 4 + a] = p;
      sd += fabsf(p - lab[a]);
    }
    labs[blk] = sd;
  }
}

// --------------------------- loss ------------------------------------------
__global__ void loss_k(const float* __restrict__ labs, const int* __restrict__ seqlen,
                       float* __restrict__ out) {
  int t = threadIdx.x;
  int b = t >> 6, l = t & 63;
  float la = (labs[(b * 64 + l) * 3] + labs[(b * 64 + l) * 3 + 1] +
              labs[(b * 64 + l) * 3 + 2]) * (1.0f / 12.0f);
  float m = (l < seqlen[b]) ? 1.f : 0.f;
  float v = la * m;
  for (int off = 32; off; off >>= 1) {
    v += __shfl_down(v, off, 64);
    m += __shfl_down(m, off, 64);
  }
  __shared__ float sb_[2];
  if ((t & 63) == 0) sb_[b] = v / fmaxf(m, 1.0f);
  __syncthreads();
  if (t == 0) out[0] = 0.5f * (sb_[0] + sb_[1]);
}

// ---------------------------------------------------------------------------
extern "C" void kernel_launch(void* const* d_in, const int* in_sizes, int n_in,
                              void* d_out, int out_size, void* d_ws, size_t ws_size,
                              hipStream_t stream) {
  const float* images     = (const float*)d_in[0];
  const int*   seq_length = (const int*)d_in[1];
  const float* states     = (const float*)d_in[2];
  const float* actions    = (const float*)d_in[3];
  const float* labels     = (const float*)d_in[4];
  const float* patch_w    = (const float*)d_in[5];
  const float* patch_b    = (const float*)d_in[6];
  const float* state_w    = (const float*)d_in[7];
  const float* state_b    = (const float*)d_in[8];
  const float* act_w      = (const float*)d_in[9];
  const float* act_b      = (const float*)d_in[10];
  const float* norm1_w    = (const float*)d_in[11];
  const float* in_proj_w  = (const float*)d_in[12];
  const float* conv_w     = (const float*)d_in[13];
  const float* conv_b     = (const float*)d_in[14];
  const float* x_proj_w   = (const float*)d_in[15];
  const float* dt_w       = (const float*)d_in[16];
  const float* dt_b       = (const float*)d_in[17];
  const float* A_log      = (const float*)d_in[18];
  const float* Dp         = (const float*)d_in[19];
  const float* out_proj_w = (const float*)d_in[20];
  const float* norm2_w    = (const float*)d_in[21];
  const float* fc1_w      = (const float*)d_in[22];
  const float* fc2_w      = (const float*)d_in[23];
  const float* norm_f_w   = (const float*)d_in[24];
  const float* head_w     = (const float*)d_in[25];
  const float* head_b     = (const float*)d_in[26];

  float* out = (float*)d_out;

  float* ws = (float*)d_ws;
  float* meanp    = ws; ws += 98304;     // (128, 768)
  float* hidden   = ws; ws += 262144;    // (512, 512)
  float* residual = ws; ws += 262144;
  float* xn       = ws; ws += 262144;
  float* xz       = ws; ws += 1048576;   // (512, 2048)
  float* xc       = ws; ws += 524288;    // (512, 1024)
  float* proj     = ws; ws += 32768;     // (512, 64)
  float* dtbuf    = ws; ws += 524288;    // (512, 1024)
  float* yz       = ws; ws += 524288;    // (512, 1024)
  float* labs     = ws; ws += 384;
  float* cpart    = ws; ws += 1048576;   // split-K partials (max 4x512x512)
  float* pmp      = ws; ws += 1376256;   // (1792, 768) patch partials

  hipLaunchKernelGGL(patch_part_k, dim3(1792), dim3(192), 0, stream, images, pmp);
  hipLaunchKernelGGL(patch_red_k, dim3(128), dim3(192), 0, stream, pmp, meanp);
  hipLaunchKernelGGL(gemm_bs_k, dim3(8, 2, 8), dim3(256), 0, stream,
                     meanp, patch_w, cpart, 128, 512, 768, 96);
  hipLaunchKernelGGL(tokenize_k, dim3(512), dim3(128), 0, stream, cpart, states, actions,
                     patch_b, state_w, state_b, act_w, act_b, hidden, residual);

  for (int i = 0; i < 8; ++i) {
    const float* n1 = norm1_w + i * 512;
    const float* ipw = in_proj_w + (size_t)i * 2048 * 512;
    const float* cw = conv_w + (size_t)i * 4096;
    const float* cb = conv_b + (size_t)i * 1024;
    const float* xpw = x_proj_w + (size_t)i * 65536;
    const float* dtw = dt_w + (size_t)i * 32768;
    const float* dtbias = dt_b + (size_t)i * 1024;
    const float* al = A_log + (size_t)i * 16384;
    const float* dpp = Dp + (size_t)i * 1024;
    const float* opw = out_proj_w + (size_t)i * 524288;
    const float* n2 = norm2_w + i * 512;
    const float* f1 = fc1_w + (size_t)i * 1048576;
    const float* f2 = fc2_w + (size_t)i * 524288;

    if (i == 0)
      hipLaunchKernelGGL(addnorm_k, dim3(512), dim3(128), 0, stream,
                         hidden, 1, residual, n1, xn);
    else
      hipLaunchKernelGGL(addnorm_k, dim3(512), dim3(128), 0, stream,
                         cpart, 4, residual, n1, xn);
    hipLaunchKernelGGL(gemm_bs_k, dim3(32, 8, 1), dim3(256), 0, stream,
                       xn, ipw, xz, 512, 2048, 512, 512);
    hipLaunchKernelGGL(convproj_k, dim3(512), dim3(256), 0, stream,
                       xz, cw, cb, xpw, dtw, dtbias, xc, proj, dtbuf);
    hipLaunchKernelGGL(scan_k, dim3(512), dim3(512), 0, stream,
                       dtbuf, proj, xc, xz, al, dpp, yz);
    hipLaunchKernelGGL(gemm_bs_k, dim3(8, 8, 4), dim3(256), 0, stream,
                       yz, opw, cpart, 512, 512, 1024, 256);
    hipLaunchKernelGGL(addnorm_k, dim3(512), dim3(128), 0, stream,
                       cpart, 4, residual, n2, xn);
    hipLaunchKernelGGL(gemm_bs_k, dim3(32, 8, 1), dim3(256), 0, stream,
                       xn, f1, xz, 512, 2048, 512, 512);
    hipLaunchKernelGGL(gemm_glu_k, dim3(8, 8, 4), dim3(256), 0, stream,
                       xz, f2, cpart, 512, 512, 1024, 256);
  }

  hipLaunchKernelGGL(addnorm_k, dim3(512), dim3(128), 0, stream,
                     cpart, 4, residual, norm_f_w, xn);
  hipLaunchKernelGGL(head_k, dim3(384), dim3(64), 0, stream, xn, head_w, head_b, labels,
                     out + 1, labs);
  hipLaunchKernelGGL(loss_k, dim3(1), dim3(128), 0, stream, labs, seq_length, out);
}